// Round 7
// baseline (446.036 us; speedup 1.0000x reference)
//
#include <hip/hip_runtime.h>
#include <hip/hip_fp16.h>

// SiameseEdgeConvNet: 2-layer EdgeConv (max aggr) on two graphs, shared weights.
// N=50000, E=1.6e6, dims 32 -> 64 -> 64.
//
// Algebra: msg = relu([xi, xj-xi] @ W + b) = relu(xi@A + xj@B + b),
//   A=W_lo-W_hi, B=W_hi.  u = x@A + b, v = x@B per node; ReLU monotone =>
//   out[d] = relu(u[d] + max_{e: dst=d} v[src_e]);  empty segment -> 0
//   (matches jax isfinite->0 fixup).  PReLU input >= 0 -> identity -> skipped.
//
// R7: node GEMMs process 4 nodes/wave/iter (R6 was 1: a 64-deep dependent
//   FMA chain at ~4cyc latency + un-prefetched row load = VALUBusy 27%,
//   87 us for ~10 us of math). 8 independent accumulator chains fill the
//   FMA pipe; 4 row loads issue back-to-back.
//   Rest unchanged from R6 (tile-binned push, fp16 v gather, LDS key atomicMax).

constexpr int HID   = 64;
constexpr int TILE  = 64;           // nodes per bucket (dst >> 6)
constexpr int ASTR  = 65;           // LDS row stride (uints): base bank = r mod 32
constexpr int MAXNB = 1024;         // max buckets (N <= 65536)
constexpr int EPT   = 16;           // edges per thread in bin_kernel

__device__ __forceinline__ unsigned int enc_key(float f) {
    unsigned int b = __float_as_uint(f);
    return (b & 0x80000000u) ? ~b : (b | 0x80000000u);
}
__device__ __forceinline__ float dec_key(unsigned int k) {
    unsigned int b = (k & 0x80000000u) ? (k ^ 0x80000000u) : ~k;
    return __uint_as_float(b);
}

struct G {                    // one graph's pointer set
    const float* x;           // [N,32] layer-1 input
    const int*   src;         // [E]
    const int*   dst;         // [E]
    int* bcnt;                // [NB]   bucket counts
    int* bptr;                // [NB+1] bucket offsets
    int* wp;                  // [NB]   bucket write pointers
    unsigned int* bin;        // [E]    packed records (src<<6 | dst&63)
    float*  u;                // [N,64] fp32
    __half* vh;               // [N,64] fp16
    float*  out;              // [N,64] — h after layer 1, final after layer 2
};

// ---- bucket histogram (LDS-staged) ----
__global__ __launch_bounds__(256) void hist_kernel(G g0, G g1, int E, int NB) {
    const G g = blockIdx.y ? g1 : g0;
    __shared__ int h[MAXNB];
    for (int i = threadIdx.x; i < NB; i += 256) h[i] = 0;
    __syncthreads();
    int i = blockIdx.x * 256 + threadIdx.x;
    const int stride = gridDim.x * 256;
    for (; i < E; i += stride) atomicAdd(&h[g.dst[i] >> 6], 1);
    __syncthreads();
    for (int t = threadIdx.x; t < NB; t += 256) {
        const int c = h[t];
        if (c) atomicAdd(&g.bcnt[t], c);
    }
}

// ---- exclusive scan over NB buckets -> bptr, wp (one block per graph) ----
__global__ __launch_bounds__(1024) void scan_kernel(G g0, G g1, int NB) {
    const G g = blockIdx.y ? g1 : g0;
    __shared__ int bufA[1024], bufB[1024];
    const int t = threadIdx.x;
    const int chunk = (NB + 1023) / 1024;
    const int beg = t * chunk, end = min(NB, beg + chunk);
    int s = 0;
    for (int i = beg; i < end; ++i) s += g.bcnt[i];
    bufA[t] = s;
    __syncthreads();
    int* in = bufA; int* out = bufB;
    for (int off = 1; off < 1024; off <<= 1) {
        out[t] = in[t] + (t >= off ? in[t - off] : 0);
        __syncthreads();
        int* tmp = in; in = out; out = tmp;
    }
    int run = (t == 0) ? 0 : in[t - 1];
    for (int i = beg; i < end; ++i) {
        g.bptr[i] = run;
        g.wp[i]   = run;
        run += g.bcnt[i];
    }
    if (t == 0) g.bptr[NB] = in[1023];
}

// ---- bin: block-reserved bucket scatter of packed records ----
__global__ __launch_bounds__(256) void bin_kernel(G g0, G g1, int E, int NB) {
    const G g = blockIdx.y ? g1 : g0;
    __shared__ int lh[MAXNB];   // local hist, then local write offset
    __shared__ int lb[MAXNB];   // reserved base per bucket
    for (int i = threadIdx.x; i < NB; i += 256) lh[i] = 0;
    __syncthreads();

    const int base = blockIdx.x * 256 * EPT;
    unsigned int rec[EPT];
    int bb[EPT];
    #pragma unroll
    for (int k = 0; k < EPT; ++k) {
        const int i = base + k * 256 + threadIdx.x;   // coalesced stream
        if (i < E) {
            const int d = g.dst[i];
            const int s = g.src[i];
            rec[k] = ((unsigned int)s << 6) | (unsigned int)(d & 63);
            bb[k]  = d >> 6;
            atomicAdd(&lh[bb[k]], 1);
        } else bb[k] = -1;
    }
    __syncthreads();
    for (int t = threadIdx.x; t < NB; t += 256) {
        const int c = lh[t];
        lb[t] = c ? atomicAdd(&g.wp[t], c) : 0;
        lh[t] = 0;
    }
    __syncthreads();
    #pragma unroll
    for (int k = 0; k < EPT; ++k) {
        if (bb[k] >= 0) {
            const int off = atomicAdd(&lh[bb[k]], 1);
            g.bin[lb[bb[k]] + off] = rec[k];
        }
    }
}

// ---- node GEMMs: u = in@A + b (fp32), v = in@B (fp16) ----
// 4 nodes per wave iteration: 8 independent FMA chains, loads batched.

__global__ __launch_bounds__(256) void gemm_uv32_kernel(
    G g0, G g1, const float* __restrict__ W, const float* __restrict__ bias, int N)
{
    const G g = blockIdx.y ? g1 : g0;
    const int lane = threadIdx.x & 63;
    const int wid  = (blockIdx.x * 256 + threadIdx.x) >> 6;
    const int nW   = (gridDim.x * 256) >> 6;

    float a_reg[32], b_reg[32];
    #pragma unroll
    for (int k = 0; k < 32; ++k) {
        const float wlo = W[k * HID + lane];
        const float whi = W[(32 + k) * HID + lane];
        a_reg[k] = wlo - whi;
        b_reg[k] = whi;
    }
    const float bv = bias[lane];
    const int lk = lane & 31;

    for (int n0 = wid * 4; n0 < N; n0 += nW * 4) {
        const int cnt = min(4, N - n0);
        float x0, x1, x2, x3;
        x0 = g.x[(size_t)n0 * 32 + lk];
        x1 = (cnt > 1) ? g.x[(size_t)(n0 + 1) * 32 + lk] : 0.f;
        x2 = (cnt > 2) ? g.x[(size_t)(n0 + 2) * 32 + lk] : 0.f;
        x3 = (cnt > 3) ? g.x[(size_t)(n0 + 3) * 32 + lk] : 0.f;
        float u0 = bv, u1 = bv, u2 = bv, u3 = bv;
        float v0 = 0.f, v1 = 0.f, v2 = 0.f, v3 = 0.f;
        #pragma unroll
        for (int k = 0; k < 32; ++k) {
            const float h0 = __shfl(x0, k), h1 = __shfl(x1, k);
            const float h2 = __shfl(x2, k), h3 = __shfl(x3, k);
            u0 = fmaf(h0, a_reg[k], u0); v0 = fmaf(h0, b_reg[k], v0);
            u1 = fmaf(h1, a_reg[k], u1); v1 = fmaf(h1, b_reg[k], v1);
            u2 = fmaf(h2, a_reg[k], u2); v2 = fmaf(h2, b_reg[k], v2);
            u3 = fmaf(h3, a_reg[k], u3); v3 = fmaf(h3, b_reg[k], v3);
        }
        g.u[(size_t)n0 * HID + lane] = u0;
        g.vh[(size_t)n0 * HID + lane] = __float2half_rn(v0);
        if (cnt > 1) { g.u[(size_t)(n0+1) * HID + lane] = u1;
                       g.vh[(size_t)(n0+1) * HID + lane] = __float2half_rn(v1); }
        if (cnt > 2) { g.u[(size_t)(n0+2) * HID + lane] = u2;
                       g.vh[(size_t)(n0+2) * HID + lane] = __float2half_rn(v2); }
        if (cnt > 3) { g.u[(size_t)(n0+3) * HID + lane] = u3;
                       g.vh[(size_t)(n0+3) * HID + lane] = __float2half_rn(v3); }
    }
}

__global__ __launch_bounds__(256) void gemm_uv64_kernel(
    G g0, G g1, const float* __restrict__ W, const float* __restrict__ bias, int N)
{
    const G g = blockIdx.y ? g1 : g0;
    const int lane = threadIdx.x & 63;
    const int wid  = (blockIdx.x * 256 + threadIdx.x) >> 6;
    const int nW   = (gridDim.x * 256) >> 6;

    float a_reg[64], b_reg[64];
    #pragma unroll
    for (int k = 0; k < 64; ++k) {
        const float wlo = W[k * HID + lane];
        const float whi = W[(64 + k) * HID + lane];
        a_reg[k] = wlo - whi;
        b_reg[k] = whi;
    }
    const float bv = bias[lane];

    for (int n0 = wid * 4; n0 < N; n0 += nW * 4) {
        const int cnt = min(4, N - n0);
        float x0, x1, x2, x3;
        x0 = g.out[(size_t)n0 * HID + lane];
        x1 = (cnt > 1) ? g.out[(size_t)(n0 + 1) * HID + lane] : 0.f;
        x2 = (cnt > 2) ? g.out[(size_t)(n0 + 2) * HID + lane] : 0.f;
        x3 = (cnt > 3) ? g.out[(size_t)(n0 + 3) * HID + lane] : 0.f;
        float u0 = bv, u1 = bv, u2 = bv, u3 = bv;
        float v0 = 0.f, v1 = 0.f, v2 = 0.f, v3 = 0.f;
        #pragma unroll
        for (int k = 0; k < 64; ++k) {
            const float h0 = __shfl(x0, k), h1 = __shfl(x1, k);
            const float h2 = __shfl(x2, k), h3 = __shfl(x3, k);
            u0 = fmaf(h0, a_reg[k], u0); v0 = fmaf(h0, b_reg[k], v0);
            u1 = fmaf(h1, a_reg[k], u1); v1 = fmaf(h1, b_reg[k], v1);
            u2 = fmaf(h2, a_reg[k], u2); v2 = fmaf(h2, b_reg[k], v2);
            u3 = fmaf(h3, a_reg[k], u3); v3 = fmaf(h3, b_reg[k], v3);
        }
        g.u[(size_t)n0 * HID + lane] = u0;
        g.vh[(size_t)n0 * HID + lane] = __float2half_rn(v0);
        if (cnt > 1) { g.u[(size_t)(n0+1) * HID + lane] = u1;
                       g.vh[(size_t)(n0+1) * HID + lane] = __float2half_rn(v1); }
        if (cnt > 2) { g.u[(size_t)(n0+2) * HID + lane] = u2;
                       g.vh[(size_t)(n0+2) * HID + lane] = __float2half_rn(v2); }
        if (cnt > 3) { g.u[(size_t)(n0+3) * HID + lane] = u3;
                       g.vh[(size_t)(n0+3) * HID + lane] = __float2half_rn(v3); }
    }
}

// ---- aggregate: one block per 64-node tile, LDS atomicMax on keys ----
__global__ __launch_bounds__(256) void agg_kernel(G g0, G g1, int N) {
    const G g = blockIdx.y ? g1 : g0;
    __shared__ unsigned int agg[TILE * ASTR];   // 64*65*4 = 16640 B
    for (int i = threadIdx.x; i < TILE * ASTR; i += 256) agg[i] = 0u;
    __syncthreads();

    const int b   = blockIdx.x;
    const int beg = g.bptr[b], end = g.bptr[b + 1];
    const int grp = threadIdx.x >> 4;           // 16 groups of 16 lanes
    const int sub = threadIdx.x & 15;
    const uint2* __restrict__ v2 = (const uint2*)g.vh;   // 8 B = 4 fp16/lane

    #define PUSH(RAW, REC)                                                   \
    {                                                                        \
        const __half2 h0 = *reinterpret_cast<const __half2*>(&(RAW).x);      \
        const __half2 h1 = *reinterpret_cast<const __half2*>(&(RAW).y);      \
        const float2 f0 = __half22float2(h0);                                \
        const float2 f1 = __half22float2(h1);                                \
        unsigned int* row = &agg[((REC) & 63u) * ASTR + sub * 4];            \
        atomicMax(row + 0, enc_key(f0.x));                                   \
        atomicMax(row + 1, enc_key(f0.y));                                   \
        atomicMax(row + 2, enc_key(f1.x));                                   \
        atomicMax(row + 3, enc_key(f1.y));                                   \
    }

    int r = beg + grp;
    for (; r + 48 < end; r += 64) {             // 4 gather chains in flight
        const unsigned int q0 = g.bin[r],      q1 = g.bin[r + 16];
        const unsigned int q2 = g.bin[r + 32], q3 = g.bin[r + 48];
        const uint2 a0 = v2[(size_t)(q0 >> 6) * 16 + sub];
        const uint2 a1 = v2[(size_t)(q1 >> 6) * 16 + sub];
        const uint2 a2 = v2[(size_t)(q2 >> 6) * 16 + sub];
        const uint2 a3 = v2[(size_t)(q3 >> 6) * 16 + sub];
        PUSH(a0, q0) PUSH(a1, q1) PUSH(a2, q2) PUSH(a3, q3)
    }
    for (; r < end; r += 16) {
        const unsigned int q0 = g.bin[r];
        const uint2 a0 = v2[(size_t)(q0 >> 6) * 16 + sub];
        PUSH(a0, q0)
    }
    #undef PUSH
    __syncthreads();

    const int nodeBase = b * TILE;
    for (int i = threadIdx.x; i < TILE * HID; i += 256) {   // 16 iters, coalesced
        const int nl = i >> 6, ch = i & 63;
        const int node = nodeBase + nl;
        if (node < N) {
            const unsigned int k = agg[nl * ASTR + ch];
            float rlt = 0.f;                                  // empty -> 0
            if (k) rlt = fmaxf(g.u[(size_t)node * HID + ch] + dec_key(k), 0.f);
            g.out[(size_t)node * HID + ch] = rlt;
        }
    }
}

// ---------------- orchestration ----------------

extern "C" void kernel_launch(void* const* d_in, const int* in_sizes, int n_in,
                              void* d_out, int out_size, void* d_ws, size_t ws_size,
                              hipStream_t stream) {
    const float* x1  = (const float*)d_in[0];
    const int*   ei1 = (const int*)d_in[1];   // [2,E]: src row then dst row
    const float* x2  = (const float*)d_in[2];
    const int*   ei2 = (const int*)d_in[3];
    const float* W1  = (const float*)d_in[4];
    const float* b1  = (const float*)d_in[5];
    // d_in[6] = prelu_a: unused (identity on >=0)
    const float* W2  = (const float*)d_in[7];
    const float* b2  = (const float*)d_in[8];

    const int N  = in_sizes[0] / 32;
    const int E  = in_sizes[1] / 2;
    const int NB = (N + TILE - 1) / TILE;     // 782 for N=50000
    float* out = (float*)d_out;

    const size_t rowB = (size_t)N * HID * sizeof(float);            // 12.8 MB
    const size_t vhB  = ((size_t)N * HID * sizeof(__half) + 63) & ~(size_t)63;
    const size_t binB = ((size_t)E * sizeof(int) + 63) & ~(size_t)63;
    const size_t nbB  = ((size_t)(NB + 2) * sizeof(int) + 63) & ~(size_t)63;

    const int hBlk = 256;
    const int bBlk = (E + 256 * EPT - 1) / (256 * EPT);
    const int gBlk = 1024;

    auto run = [&](G ga, G gb, int ny) {
        // bcnt arrays contiguous across graphs: one memset when ny==2
        hipMemsetAsync(ga.bcnt, 0, (size_t)ny * nbB, stream);
        hist_kernel<<<dim3(hBlk, ny), 256, 0, stream>>>(ga, gb, E, NB);
        scan_kernel<<<dim3(1, ny), 1024, 0, stream>>>(ga, gb, NB);
        bin_kernel <<<dim3(bBlk, ny), 256, 0, stream>>>(ga, gb, E, NB);
        gemm_uv32_kernel<<<dim3(gBlk, ny), 256, 0, stream>>>(ga, gb, W1, b1, N);
        agg_kernel      <<<dim3(NB,   ny), 256, 0, stream>>>(ga, gb, N);
        gemm_uv64_kernel<<<dim3(gBlk, ny), 256, 0, stream>>>(ga, gb, W2, b2, N);
        agg_kernel      <<<dim3(NB,   ny), 256, 0, stream>>>(ga, gb, N);
    };

    char* ws = (char*)d_ws;
    const size_t needBoth = 2 * rowB + 2 * vhB + 2 * binB + 6 * nbB;

    if (ws_size >= needBoth) {
        float* u0 = (float*)ws;                  ws += rowB;
        float* u1 = (float*)ws;                  ws += rowB;
        unsigned int* bin0 = (unsigned int*)ws;  ws += binB;
        unsigned int* bin1 = (unsigned int*)ws;  ws += binB;
        __half* vh0 = (__half*)ws;               ws += vhB;
        __half* vh1 = (__half*)ws;               ws += vhB;
        int* bcnt0 = (int*)ws;                   ws += nbB;
        int* bcnt1 = (int*)ws;                   ws += nbB;   // contiguous with bcnt0
        int* bptr0 = (int*)ws;                   ws += nbB;
        int* bptr1 = (int*)ws;                   ws += nbB;
        int* wp0   = (int*)ws;                   ws += nbB;
        int* wp1   = (int*)ws;

        G g0{x1, ei1, ei1 + E, bcnt0, bptr0, wp0, bin0, u0, vh0, out};
        G g1{x2, ei2, ei2 + E, bcnt1, bptr1, wp1, bin1, u1, vh1,
             out + (size_t)N * HID};
        run(g0, g1, 2);
    } else {
        // sequential fallback (~26 MB): one graph's buffers, reused
        float* u = (float*)ws;                   ws += rowB;
        unsigned int* bin = (unsigned int*)ws;   ws += binB;
        __half* vh = (__half*)ws;                ws += vhB;
        int* bcnt = (int*)ws;                    ws += nbB;
        int* bptr = (int*)ws;                    ws += nbB;
        int* wp   = (int*)ws;

        for (int g = 0; g < 2; ++g) {
            const int* ei = g ? ei2 : ei1;
            G gp{g ? x2 : x1, ei, ei + E, bcnt, bptr, wp, bin,
                 u, vh, out + (size_t)g * N * HID};
            run(gp, gp, 1);
        }
    }
}

// Round 8
// 294.217 us; speedup vs baseline: 1.5160x; 1.5160x over previous
//
#include <hip/hip_runtime.h>
#include <hip/hip_fp16.h>

// SiameseEdgeConvNet: 2-layer EdgeConv (max aggr) on two graphs, shared weights.
// N=50000, E=1.6e6, dims 32 -> 64 -> 64.
//
// Algebra: msg = relu([xi, xj-xi] @ W + b) = relu(xi@A + xj@B + b),
//   A=W_lo-W_hi, B=W_hi.  u = x@A + b, v = x@B per node; ReLU monotone =>
//   out[d] = relu(u[d] + max_{e: dst=d} v[src_e]);  empty segment -> 0
//   (matches jax isfinite->0 fixup).  PReLU input >= 0 -> identity -> skipped.
//
// R8: node GEMMs moved to MFMA (v_mfma_f32_16x16x32_f16, fp32 accumulate).
//   R6/R7's shfl-broadcast VALU GEMM was register-starved (R7: VGPR 212,
//   Occ 11%, 151 us for ~10 us of math). Combined weight Wc=[A|B] fp16
//   [K x 128] built once by prep_w. Per wave: 16-node tile, 8 col-tiles,
//   B-frags in regs across the kernel. Layouts (m89/m120-verified):
//     A[m=lane&15][k=quad*8+j], B[k=quad*8+j][n=lane&15],
//     D[m=quad*4+reg][n=lane&15].
//   Rest identical to R6 (tile-binned push, fp16 v gather, LDS key atomicMax).

constexpr int HID   = 64;
constexpr int TILE  = 64;           // nodes per bucket (dst >> 6)
constexpr int ASTR  = 65;           // LDS row stride (uints): base bank = r mod 32
constexpr int MAXNB = 1024;         // max buckets (N <= 65536)
constexpr int EPT   = 16;           // edges per thread in bin_kernel

typedef _Float16 half8 __attribute__((ext_vector_type(8)));
typedef float    f32x4 __attribute__((ext_vector_type(4)));

__device__ __forceinline__ unsigned int enc_key(float f) {
    unsigned int b = __float_as_uint(f);
    return (b & 0x80000000u) ? ~b : (b | 0x80000000u);
}
__device__ __forceinline__ float dec_key(unsigned int k) {
    unsigned int b = (k & 0x80000000u) ? (k ^ 0x80000000u) : ~k;
    return __uint_as_float(b);
}

struct G {                    // one graph's pointer set
    const float* x;           // [N,32] layer-1 input
    const int*   src;         // [E]
    const int*   dst;         // [E]
    int* bcnt;                // [NB]   bucket counts
    int* bptr;                // [NB+1] bucket offsets
    int* wp;                  // [NB]   bucket write pointers
    unsigned int* bin;        // [E]    packed records (src<<6 | dst&63)
    float*  u;                // [N,64] fp32
    __half* vh;               // [N,64] fp16
    float*  out;              // [N,64] — h after layer 1, final after layer 2
};

// ---- weight prep: Wc[k][c] = (c<64 ? W_lo-W_hi : W_hi) in fp16, [K x 128] ----
__global__ __launch_bounds__(256) void prep_w_kernel(
    const float* __restrict__ W1, const float* __restrict__ W2,
    _Float16* __restrict__ Wc1, _Float16* __restrict__ Wc2)
{
    const int i = blockIdx.x * 256 + threadIdx.x;
    if (i < 32 * 64) {
        const int k = i >> 6, c = i & 63;
        const float lo = W1[k * 64 + c], hi = W1[(32 + k) * 64 + c];
        Wc1[k * 128 + c]      = (_Float16)(lo - hi);
        Wc1[k * 128 + 64 + c] = (_Float16)hi;
    }
    const int j = i - 32 * 64;
    if (j >= 0 && j < 64 * 64) {
        const int k = j >> 6, c = j & 63;
        const float lo = W2[k * 64 + c], hi = W2[(64 + k) * 64 + c];
        Wc2[k * 128 + c]      = (_Float16)(lo - hi);
        Wc2[k * 128 + 64 + c] = (_Float16)hi;
    }
}

// ---- bucket histogram (LDS-staged) ----
__global__ __launch_bounds__(256) void hist_kernel(G g0, G g1, int E, int NB) {
    const G g = blockIdx.y ? g1 : g0;
    __shared__ int h[MAXNB];
    for (int i = threadIdx.x; i < NB; i += 256) h[i] = 0;
    __syncthreads();
    int i = blockIdx.x * 256 + threadIdx.x;
    const int stride = gridDim.x * 256;
    for (; i < E; i += stride) atomicAdd(&h[g.dst[i] >> 6], 1);
    __syncthreads();
    for (int t = threadIdx.x; t < NB; t += 256) {
        const int c = h[t];
        if (c) atomicAdd(&g.bcnt[t], c);
    }
}

// ---- exclusive scan over NB buckets -> bptr, wp (one block per graph) ----
__global__ __launch_bounds__(1024) void scan_kernel(G g0, G g1, int NB) {
    const G g = blockIdx.y ? g1 : g0;
    __shared__ int bufA[1024], bufB[1024];
    const int t = threadIdx.x;
    const int chunk = (NB + 1023) / 1024;
    const int beg = t * chunk, end = min(NB, beg + chunk);
    int s = 0;
    for (int i = beg; i < end; ++i) s += g.bcnt[i];
    bufA[t] = s;
    __syncthreads();
    int* in = bufA; int* out = bufB;
    for (int off = 1; off < 1024; off <<= 1) {
        out[t] = in[t] + (t >= off ? in[t - off] : 0);
        __syncthreads();
        int* tmp = in; in = out; out = tmp;
    }
    int run = (t == 0) ? 0 : in[t - 1];
    for (int i = beg; i < end; ++i) {
        g.bptr[i] = run;
        g.wp[i]   = run;
        run += g.bcnt[i];
    }
    if (t == 0) g.bptr[NB] = in[1023];
}

// ---- bin: block-reserved bucket scatter of packed records ----
__global__ __launch_bounds__(256) void bin_kernel(G g0, G g1, int E, int NB) {
    const G g = blockIdx.y ? g1 : g0;
    __shared__ int lh[MAXNB];   // local hist, then local write offset
    __shared__ int lb[MAXNB];   // reserved base per bucket
    for (int i = threadIdx.x; i < NB; i += 256) lh[i] = 0;
    __syncthreads();

    const int base = blockIdx.x * 256 * EPT;
    unsigned int rec[EPT];
    int bb[EPT];
    #pragma unroll
    for (int k = 0; k < EPT; ++k) {
        const int i = base + k * 256 + threadIdx.x;   // coalesced stream
        if (i < E) {
            const int d = g.dst[i];
            const int s = g.src[i];
            rec[k] = ((unsigned int)s << 6) | (unsigned int)(d & 63);
            bb[k]  = d >> 6;
            atomicAdd(&lh[bb[k]], 1);
        } else bb[k] = -1;
    }
    __syncthreads();
    for (int t = threadIdx.x; t < NB; t += 256) {
        const int c = lh[t];
        lb[t] = c ? atomicAdd(&g.wp[t], c) : 0;
        lh[t] = 0;
    }
    __syncthreads();
    #pragma unroll
    for (int k = 0; k < EPT; ++k) {
        if (bb[k] >= 0) {
            const int off = atomicAdd(&lh[bb[k]], 1);
            g.bin[lb[bb[k]] + off] = rec[k];
        }
    }
}

// ---- MFMA node GEMM: [u|v](N x 128) = in(N x K) @ Wc(K x 128); u += bias ----
// One 16-node tile per wave iteration; B-frags persistent in registers.
template<int K>
__global__ __launch_bounds__(256) void gemm_mfma_kernel(
    G g0, G g1, const _Float16* __restrict__ Wc,
    const float* __restrict__ bias, int N)
{
    const G g = blockIdx.y ? g1 : g0;
    constexpr int KH = K / 32;                 // k-halves (1 or 2)
    const int lane = threadIdx.x & 63;
    const int m    = lane & 15;                // A row / D col-lane
    const int quad = lane >> 4;
    const int wid  = (blockIdx.x * 256 + threadIdx.x) >> 6;
    const int nW   = (gridDim.x * 256) >> 6;

    // B-frags: B[k=32h+quad*8+j][n=16t+m]
    half8 bf[8][KH];
    #pragma unroll
    for (int t = 0; t < 8; ++t)
        #pragma unroll
        for (int h = 0; h < KH; ++h)
            #pragma unroll
            for (int j = 0; j < 8; ++j)
                bf[t][h][j] = Wc[(h * 32 + quad * 8 + j) * 128 + t * 16 + m];

    float bv[4];
    #pragma unroll
    for (int t = 0; t < 4; ++t) bv[t] = bias[t * 16 + m];

    const float* __restrict__ inp = (K == 32) ? g.x : g.out;
    const int tiles = (N + 15) / 16;

    for (int tile = wid; tile < tiles; tile += nW) {
        const int nbase = tile * 16;
        const int nodeA = min(nbase + m, N - 1);
        const float4* rp = (const float4*)(inp + (size_t)nodeA * K);

        half8 a[KH];
        #pragma unroll
        for (int h = 0; h < KH; ++h) {
            const float4 f0 = rp[h * 8 + quad * 2];
            const float4 f1 = rp[h * 8 + quad * 2 + 1];
            a[h][0] = (_Float16)f0.x; a[h][1] = (_Float16)f0.y;
            a[h][2] = (_Float16)f0.z; a[h][3] = (_Float16)f0.w;
            a[h][4] = (_Float16)f1.x; a[h][5] = (_Float16)f1.y;
            a[h][6] = (_Float16)f1.z; a[h][7] = (_Float16)f1.w;
        }

        f32x4 acc[8];
        #pragma unroll
        for (int t = 0; t < 8; ++t) {
            acc[t] = (f32x4){0.f, 0.f, 0.f, 0.f};
            #pragma unroll
            for (int h = 0; h < KH; ++h)
                acc[t] = __builtin_amdgcn_mfma_f32_16x16x32_f16(
                    a[h], bf[t][h], acc[t], 0, 0, 0);
        }

        // D[m=quad*4+r][n=lane&15]
        #pragma unroll
        for (int r = 0; r < 4; ++r) {
            const int node = nbase + quad * 4 + r;
            if (node < N) {
                float* urow = g.u + (size_t)node * HID;
                __half* vrow = g.vh + (size_t)node * HID;
                #pragma unroll
                for (int t = 0; t < 4; ++t)
                    urow[t * 16 + m] = acc[t][r] + bv[t];
                #pragma unroll
                for (int t = 4; t < 8; ++t)
                    vrow[(t - 4) * 16 + m] = __float2half_rn(acc[t][r]);
            }
        }
    }
}

// ---- aggregate: one block per 64-node tile, LDS atomicMax on keys ----
__global__ __launch_bounds__(256) void agg_kernel(G g0, G g1, int N) {
    const G g = blockIdx.y ? g1 : g0;
    __shared__ unsigned int agg[TILE * ASTR];   // 64*65*4 = 16640 B
    for (int i = threadIdx.x; i < TILE * ASTR; i += 256) agg[i] = 0u;
    __syncthreads();

    const int b   = blockIdx.x;
    const int beg = g.bptr[b], end = g.bptr[b + 1];
    const int grp = threadIdx.x >> 4;           // 16 groups of 16 lanes
    const int sub = threadIdx.x & 15;
    const uint2* __restrict__ v2 = (const uint2*)g.vh;   // 8 B = 4 fp16/lane

    #define PUSH(RAW, REC)                                                   \
    {                                                                        \
        const __half2 h0 = *reinterpret_cast<const __half2*>(&(RAW).x);      \
        const __half2 h1 = *reinterpret_cast<const __half2*>(&(RAW).y);      \
        const float2 f0 = __half22float2(h0);                                \
        const float2 f1 = __half22float2(h1);                                \
        unsigned int* row = &agg[((REC) & 63u) * ASTR + sub * 4];            \
        atomicMax(row + 0, enc_key(f0.x));                                   \
        atomicMax(row + 1, enc_key(f0.y));                                   \
        atomicMax(row + 2, enc_key(f1.x));                                   \
        atomicMax(row + 3, enc_key(f1.y));                                   \
    }

    int r = beg + grp;
    for (; r + 48 < end; r += 64) {             // 4 gather chains in flight
        const unsigned int q0 = g.bin[r],      q1 = g.bin[r + 16];
        const unsigned int q2 = g.bin[r + 32], q3 = g.bin[r + 48];
        const uint2 a0 = v2[(size_t)(q0 >> 6) * 16 + sub];
        const uint2 a1 = v2[(size_t)(q1 >> 6) * 16 + sub];
        const uint2 a2 = v2[(size_t)(q2 >> 6) * 16 + sub];
        const uint2 a3 = v2[(size_t)(q3 >> 6) * 16 + sub];
        PUSH(a0, q0) PUSH(a1, q1) PUSH(a2, q2) PUSH(a3, q3)
    }
    for (; r < end; r += 16) {
        const unsigned int q0 = g.bin[r];
        const uint2 a0 = v2[(size_t)(q0 >> 6) * 16 + sub];
        PUSH(a0, q0)
    }
    #undef PUSH
    __syncthreads();

    const int nodeBase = b * TILE;
    for (int i = threadIdx.x; i < TILE * HID; i += 256) {   // 16 iters, coalesced
        const int nl = i >> 6, ch = i & 63;
        const int node = nodeBase + nl;
        if (node < N) {
            const unsigned int k = agg[nl * ASTR + ch];
            float rlt = 0.f;                                  // empty -> 0
            if (k) rlt = fmaxf(g.u[(size_t)node * HID + ch] + dec_key(k), 0.f);
            g.out[(size_t)node * HID + ch] = rlt;
        }
    }
}

// ---------------- orchestration ----------------

extern "C" void kernel_launch(void* const* d_in, const int* in_sizes, int n_in,
                              void* d_out, int out_size, void* d_ws, size_t ws_size,
                              hipStream_t stream) {
    const float* x1  = (const float*)d_in[0];
    const int*   ei1 = (const int*)d_in[1];   // [2,E]: src row then dst row
    const float* x2  = (const float*)d_in[2];
    const int*   ei2 = (const int*)d_in[3];
    const float* W1  = (const float*)d_in[4];
    const float* b1  = (const float*)d_in[5];
    // d_in[6] = prelu_a: unused (identity on >=0)
    const float* W2  = (const float*)d_in[7];
    const float* b2  = (const float*)d_in[8];

    const int N  = in_sizes[0] / 32;
    const int E  = in_sizes[1] / 2;
    const int NB = (N + TILE - 1) / TILE;     // 782 for N=50000
    float* out = (float*)d_out;

    const size_t rowB = (size_t)N * HID * sizeof(float);            // 12.8 MB
    const size_t vhB  = ((size_t)N * HID * sizeof(__half) + 63) & ~(size_t)63;
    const size_t binB = ((size_t)E * sizeof(int) + 63) & ~(size_t)63;
    const size_t nbB  = ((size_t)(NB + 2) * sizeof(int) + 63) & ~(size_t)63;
    const size_t wc1B = ((size_t)32 * 128 * 2 + 63) & ~(size_t)63;
    const size_t wc2B = ((size_t)64 * 128 * 2 + 63) & ~(size_t)63;

    const int hBlk = 256;
    const int bBlk = (E + 256 * EPT - 1) / (256 * EPT);
    const int gBlk = 128;                     // mfma gemm: ~6 tiles/wave
    const int pBlk = (32 * 64 + 64 * 64 + 255) / 256;

    _Float16* wc1 = nullptr;
    _Float16* wc2 = nullptr;

    auto run = [&](G ga, G gb, int ny) {
        // bcnt arrays contiguous across graphs: one memset when ny==2
        hipMemsetAsync(ga.bcnt, 0, (size_t)ny * nbB, stream);
        hist_kernel<<<dim3(hBlk, ny), 256, 0, stream>>>(ga, gb, E, NB);
        scan_kernel<<<dim3(1, ny), 1024, 0, stream>>>(ga, gb, NB);
        bin_kernel <<<dim3(bBlk, ny), 256, 0, stream>>>(ga, gb, E, NB);
        gemm_mfma_kernel<32><<<dim3(gBlk, ny), 256, 0, stream>>>(ga, gb, wc1, b1, N);
        agg_kernel          <<<dim3(NB,   ny), 256, 0, stream>>>(ga, gb, N);
        gemm_mfma_kernel<64><<<dim3(gBlk, ny), 256, 0, stream>>>(ga, gb, wc2, b2, N);
        agg_kernel          <<<dim3(NB,   ny), 256, 0, stream>>>(ga, gb, N);
    };

    char* ws = (char*)d_ws;
    const size_t needBoth = 2 * rowB + 2 * vhB + 2 * binB + 6 * nbB + wc1B + wc2B;

    if (ws_size >= needBoth) {
        float* u0 = (float*)ws;                  ws += rowB;
        float* u1 = (float*)ws;                  ws += rowB;
        unsigned int* bin0 = (unsigned int*)ws;  ws += binB;
        unsigned int* bin1 = (unsigned int*)ws;  ws += binB;
        __half* vh0 = (__half*)ws;               ws += vhB;
        __half* vh1 = (__half*)ws;               ws += vhB;
        wc1 = (_Float16*)ws;                     ws += wc1B;
        wc2 = (_Float16*)ws;                     ws += wc2B;
        int* bcnt0 = (int*)ws;                   ws += nbB;
        int* bcnt1 = (int*)ws;                   ws += nbB;   // contiguous with bcnt0
        int* bptr0 = (int*)ws;                   ws += nbB;
        int* bptr1 = (int*)ws;                   ws += nbB;
        int* wp0   = (int*)ws;                   ws += nbB;
        int* wp1   = (int*)ws;

        G g0{x1, ei1, ei1 + E, bcnt0, bptr0, wp0, bin0, u0, vh0, out};
        G g1{x2, ei2, ei2 + E, bcnt1, bptr1, wp1, bin1, u1, vh1,
             out + (size_t)N * HID};
        prep_w_kernel<<<pBlk, 256, 0, stream>>>(W1, W2, wc1, wc2);
        run(g0, g1, 2);
    } else {
        // sequential fallback (~26 MB): one graph's buffers, reused
        float* u = (float*)ws;                   ws += rowB;
        unsigned int* bin = (unsigned int*)ws;   ws += binB;
        __half* vh = (__half*)ws;                ws += vhB;
        wc1 = (_Float16*)ws;                     ws += wc1B;
        wc2 = (_Float16*)ws;                     ws += wc2B;
        int* bcnt = (int*)ws;                    ws += nbB;
        int* bptr = (int*)ws;                    ws += nbB;
        int* wp   = (int*)ws;

        prep_w_kernel<<<pBlk, 256, 0, stream>>>(W1, W2, wc1, wc2);
        for (int g = 0; g < 2; ++g) {
            const int* ei = g ? ei2 : ei1;
            G gp{g ? x2 : x1, ei, ei + E, bcnt, bptr, wp, bin,
                 u, vh, out + (size_t)g * N * HID};
            run(gp, gp, 1);
        }
    }
}

// Round 9
// 286.936 us; speedup vs baseline: 1.5545x; 1.0254x over previous
//
#include <hip/hip_runtime.h>
#include <hip/hip_fp16.h>

// SiameseEdgeConvNet: 2-layer EdgeConv (max aggr) on two graphs, shared weights.
// N=50000, E=1.6e6, dims 32 -> 64 -> 64.
//
// Algebra: msg = relu([xi, xj-xi] @ W + b) = relu(xi@A + xj@B + b),
//   A=W_lo-W_hi, B=W_hi.  u = x@A + b, v = x@B per node; ReLU monotone =>
//   out[d] = relu(u[d] + max_{e: dst=d} v[src_e]);  empty segment -> 0
//   (matches jax isfinite->0 fixup).  PReLU input >= 0 -> identity -> skipped.
//
// R9 (on R8's MFMA-gemm + tile-binned push):
//   * v stored as PRE-ENCODED fp16 sort keys (b<0 ? ~b : b|0x8000; key 0 =
//     -NaN = empty sentinel), computed in the gemm epilogue. agg's per-edge
//     work: one 8B load + 2 VALU (<<16, &0xFFFF0000) + 4 LDS atomicMax
//     (was ~20 VALU of cvt+enc; VALUBusy 54%).
//   * channel-permuted vk layout (position 4m+t = channel 16t+m): lane sub's
//     atomics land at row + sub + 16i -> 16 consecutive banks per group
//     (was sub*4+i -> 8 banks, 4-8-way conflicts, 9.6e6 conflict cycles).
//   Identical fp16-max numerics to R8.

constexpr int HID   = 64;
constexpr int TILE  = 64;           // nodes per bucket (dst >> 6)
constexpr int ASTR  = 65;           // LDS row stride (uints): base bank = r mod 32
constexpr int MAXNB = 1024;         // max buckets (N <= 65536)
constexpr int EPT   = 16;           // edges per thread in bin_kernel

typedef _Float16 half8 __attribute__((ext_vector_type(8)));
typedef float    f32x4 __attribute__((ext_vector_type(4)));

__device__ __forceinline__ unsigned short enc16(float f) {
    const __half h = __float2half_rn(f);
    const unsigned short b = *reinterpret_cast<const unsigned short*>(&h);
    return (b & 0x8000u) ? (unsigned short)~b : (unsigned short)(b | 0x8000u);
}
__device__ __forceinline__ float dec16(unsigned short k) {
    const unsigned short b =
        (k & 0x8000u) ? (unsigned short)(k ^ 0x8000u) : (unsigned short)~k;
    __half h;
    *reinterpret_cast<unsigned short*>(&h) = b;
    return __half2float(h);
}

struct G {                    // one graph's pointer set
    const float* x;           // [N,32] layer-1 input
    const int*   src;         // [E]
    const int*   dst;         // [E]
    int* bcnt;                // [NB]   bucket counts
    int* bptr;                // [NB+1] bucket offsets
    int* wp;                  // [NB]   bucket write pointers
    unsigned int* bin;        // [E]    packed records (src<<6 | dst&63)
    float*          u;        // [N,64] fp32
    unsigned short* vk;       // [N,64] fp16 sort keys, channel-permuted
    float*          out;      // [N,64] — h after layer 1, final after layer 2
};

// ---- weight prep: Wc[k][c] = (c<64 ? W_lo-W_hi : W_hi) in fp16, [K x 128] ----
__global__ __launch_bounds__(256) void prep_w_kernel(
    const float* __restrict__ W1, const float* __restrict__ W2,
    _Float16* __restrict__ Wc1, _Float16* __restrict__ Wc2)
{
    const int i = blockIdx.x * 256 + threadIdx.x;
    if (i < 32 * 64) {
        const int k = i >> 6, c = i & 63;
        const float lo = W1[k * 64 + c], hi = W1[(32 + k) * 64 + c];
        Wc1[k * 128 + c]      = (_Float16)(lo - hi);
        Wc1[k * 128 + 64 + c] = (_Float16)hi;
    }
    const int j = i - 32 * 64;
    if (j >= 0 && j < 64 * 64) {
        const int k = j >> 6, c = j & 63;
        const float lo = W2[k * 64 + c], hi = W2[(64 + k) * 64 + c];
        Wc2[k * 128 + c]      = (_Float16)(lo - hi);
        Wc2[k * 128 + 64 + c] = (_Float16)hi;
    }
}

// ---- bucket histogram (LDS-staged) ----
__global__ __launch_bounds__(256) void hist_kernel(G g0, G g1, int E, int NB) {
    const G g = blockIdx.y ? g1 : g0;
    __shared__ int h[MAXNB];
    for (int i = threadIdx.x; i < NB; i += 256) h[i] = 0;
    __syncthreads();
    int i = blockIdx.x * 256 + threadIdx.x;
    const int stride = gridDim.x * 256;
    for (; i < E; i += stride) atomicAdd(&h[g.dst[i] >> 6], 1);
    __syncthreads();
    for (int t = threadIdx.x; t < NB; t += 256) {
        const int c = h[t];
        if (c) atomicAdd(&g.bcnt[t], c);
    }
}

// ---- exclusive scan over NB buckets -> bptr, wp (one block per graph) ----
__global__ __launch_bounds__(1024) void scan_kernel(G g0, G g1, int NB) {
    const G g = blockIdx.y ? g1 : g0;
    __shared__ int bufA[1024], bufB[1024];
    const int t = threadIdx.x;
    const int chunk = (NB + 1023) / 1024;
    const int beg = t * chunk, end = min(NB, beg + chunk);
    int s = 0;
    for (int i = beg; i < end; ++i) s += g.bcnt[i];
    bufA[t] = s;
    __syncthreads();
    int* in = bufA; int* out = bufB;
    for (int off = 1; off < 1024; off <<= 1) {
        out[t] = in[t] + (t >= off ? in[t - off] : 0);
        __syncthreads();
        int* tmp = in; in = out; out = tmp;
    }
    int run = (t == 0) ? 0 : in[t - 1];
    for (int i = beg; i < end; ++i) {
        g.bptr[i] = run;
        g.wp[i]   = run;
        run += g.bcnt[i];
    }
    if (t == 0) g.bptr[NB] = in[1023];
}

// ---- bin: block-reserved bucket scatter of packed records ----
__global__ __launch_bounds__(256) void bin_kernel(G g0, G g1, int E, int NB) {
    const G g = blockIdx.y ? g1 : g0;
    __shared__ int lh[MAXNB];   // local hist, then local write offset
    __shared__ int lb[MAXNB];   // reserved base per bucket
    for (int i = threadIdx.x; i < NB; i += 256) lh[i] = 0;
    __syncthreads();

    const int base = blockIdx.x * 256 * EPT;
    unsigned int rec[EPT];
    int bb[EPT];
    #pragma unroll
    for (int k = 0; k < EPT; ++k) {
        const int i = base + k * 256 + threadIdx.x;   // coalesced stream
        if (i < E) {
            const int d = g.dst[i];
            const int s = g.src[i];
            rec[k] = ((unsigned int)s << 6) | (unsigned int)(d & 63);
            bb[k]  = d >> 6;
            atomicAdd(&lh[bb[k]], 1);
        } else bb[k] = -1;
    }
    __syncthreads();
    for (int t = threadIdx.x; t < NB; t += 256) {
        const int c = lh[t];
        lb[t] = c ? atomicAdd(&g.wp[t], c) : 0;
        lh[t] = 0;
    }
    __syncthreads();
    #pragma unroll
    for (int k = 0; k < EPT; ++k) {
        if (bb[k] >= 0) {
            const int off = atomicAdd(&lh[bb[k]], 1);
            g.bin[lb[bb[k]] + off] = rec[k];
        }
    }
}

// ---- MFMA node GEMM: [u|v](N x 128) = in(N x K) @ Wc(K x 128); u += bias ----
// v is emitted as fp16 sort keys in channel-permuted order:
//   uint2 slot m of a row = channels {m, m+16, m+32, m+48}.
template<int K>
__global__ __launch_bounds__(256) void gemm_mfma_kernel(
    G g0, G g1, const _Float16* __restrict__ Wc,
    const float* __restrict__ bias, int N)
{
    const G g = blockIdx.y ? g1 : g0;
    constexpr int KH = K / 32;                 // k-halves (1 or 2)
    const int lane = threadIdx.x & 63;
    const int m    = lane & 15;                // A row / D col-lane
    const int quad = lane >> 4;
    const int wid  = (blockIdx.x * 256 + threadIdx.x) >> 6;
    const int nW   = (gridDim.x * 256) >> 6;

    // B-frags: B[k=32h+quad*8+j][n=16t+m]
    half8 bf[8][KH];
    #pragma unroll
    for (int t = 0; t < 8; ++t)
        #pragma unroll
        for (int h = 0; h < KH; ++h)
            #pragma unroll
            for (int j = 0; j < 8; ++j)
                bf[t][h][j] = Wc[(h * 32 + quad * 8 + j) * 128 + t * 16 + m];

    float bv[4];
    #pragma unroll
    for (int t = 0; t < 4; ++t) bv[t] = bias[t * 16 + m];

    const float* __restrict__ inp = (K == 32) ? g.x : g.out;
    const int tiles = (N + 15) / 16;

    for (int tile = wid; tile < tiles; tile += nW) {
        const int nbase = tile * 16;
        const int nodeA = min(nbase + m, N - 1);
        const float4* rp = (const float4*)(inp + (size_t)nodeA * K);

        half8 a[KH];
        #pragma unroll
        for (int h = 0; h < KH; ++h) {
            const float4 f0 = rp[h * 8 + quad * 2];
            const float4 f1 = rp[h * 8 + quad * 2 + 1];
            a[h][0] = (_Float16)f0.x; a[h][1] = (_Float16)f0.y;
            a[h][2] = (_Float16)f0.z; a[h][3] = (_Float16)f0.w;
            a[h][4] = (_Float16)f1.x; a[h][5] = (_Float16)f1.y;
            a[h][6] = (_Float16)f1.z; a[h][7] = (_Float16)f1.w;
        }

        f32x4 acc[8];
        #pragma unroll
        for (int t = 0; t < 8; ++t) {
            acc[t] = (f32x4){0.f, 0.f, 0.f, 0.f};
            #pragma unroll
            for (int h = 0; h < KH; ++h)
                acc[t] = __builtin_amdgcn_mfma_f32_16x16x32_f16(
                    a[h], bf[t][h], acc[t], 0, 0, 0);
        }

        // D[m=quad*4+r][n=lane&15]
        #pragma unroll
        for (int r = 0; r < 4; ++r) {
            const int node = nbase + quad * 4 + r;
            if (node < N) {
                float* urow = g.u + (size_t)node * HID;
                #pragma unroll
                for (int t = 0; t < 4; ++t)
                    urow[t * 16 + m] = acc[t][r] + bv[t];
                // v: keys for channels {m, m+16, m+32, m+48} -> uint2 slot m
                const unsigned int e0 = enc16(acc[4][r]);
                const unsigned int e1 = enc16(acc[5][r]);
                const unsigned int e2 = enc16(acc[6][r]);
                const unsigned int e3 = enc16(acc[7][r]);
                uint2 pack;
                pack.x = (e1 << 16) | e0;
                pack.y = (e3 << 16) | e2;
                ((uint2*)(g.vk + (size_t)node * HID))[m] = pack;
            }
        }
    }
}

// ---- aggregate: one block per 64-node tile, LDS atomicMax on 32-bit keys ----
__global__ __launch_bounds__(256) void agg_kernel(G g0, G g1, int N) {
    const G g = blockIdx.y ? g1 : g0;
    __shared__ unsigned int agg[TILE * ASTR];   // 64*65*4 = 16640 B
    for (int i = threadIdx.x; i < TILE * ASTR; i += 256) agg[i] = 0u;
    __syncthreads();

    const int b   = blockIdx.x;
    const int beg = g.bptr[b], end = g.bptr[b + 1];
    const int grp = threadIdx.x >> 4;           // 16 groups of 16 lanes
    const int sub = threadIdx.x & 15;
    const uint2* __restrict__ vk2 = (const uint2*)g.vk;  // 8 B = 4 keys/lane

    // channels {sub, sub+16, sub+32, sub+48}: atomics at row + sub + 16i
    // -> 16 consecutive banks per group (free-ish 2-way overlap across groups)
    #define PUSH(RAW, REC)                                                   \
    {                                                                        \
        unsigned int* row = &agg[((REC) & 63u) * ASTR + sub];                \
        atomicMax(row,      (RAW).x << 16);                                  \
        atomicMax(row + 16, (RAW).x & 0xFFFF0000u);                          \
        atomicMax(row + 32, (RAW).y << 16);                                  \
        atomicMax(row + 48, (RAW).y & 0xFFFF0000u);                          \
    }

    int r = beg + grp;
    for (; r + 48 < end; r += 64) {             // 4 gather chains in flight
        const unsigned int q0 = g.bin[r],      q1 = g.bin[r + 16];
        const unsigned int q2 = g.bin[r + 32], q3 = g.bin[r + 48];
        const uint2 a0 = vk2[(size_t)(q0 >> 6) * 16 + sub];
        const uint2 a1 = vk2[(size_t)(q1 >> 6) * 16 + sub];
        const uint2 a2 = vk2[(size_t)(q2 >> 6) * 16 + sub];
        const uint2 a3 = vk2[(size_t)(q3 >> 6) * 16 + sub];
        PUSH(a0, q0) PUSH(a1, q1) PUSH(a2, q2) PUSH(a3, q3)
    }
    for (; r < end; r += 16) {
        const unsigned int q0 = g.bin[r];
        const uint2 a0 = vk2[(size_t)(q0 >> 6) * 16 + sub];
        PUSH(a0, q0)
    }
    #undef PUSH
    __syncthreads();

    const int nodeBase = b * TILE;
    for (int i = threadIdx.x; i < TILE * HID; i += 256) {   // 16 iters, coalesced
        const int nl = i >> 6, ch = i & 63;
        const int node = nodeBase + nl;
        if (node < N) {
            const unsigned int k = agg[nl * ASTR + ch];
            float rlt = 0.f;                                  // empty -> 0
            if (k) rlt = fmaxf(g.u[(size_t)node * HID + ch] +
                               dec16((unsigned short)(k >> 16)), 0.f);
            g.out[(size_t)node * HID + ch] = rlt;
        }
    }
}

// ---------------- orchestration ----------------

extern "C" void kernel_launch(void* const* d_in, const int* in_sizes, int n_in,
                              void* d_out, int out_size, void* d_ws, size_t ws_size,
                              hipStream_t stream) {
    const float* x1  = (const float*)d_in[0];
    const int*   ei1 = (const int*)d_in[1];   // [2,E]: src row then dst row
    const float* x2  = (const float*)d_in[2];
    const int*   ei2 = (const int*)d_in[3];
    const float* W1  = (const float*)d_in[4];
    const float* b1  = (const float*)d_in[5];
    // d_in[6] = prelu_a: unused (identity on >=0)
    const float* W2  = (const float*)d_in[7];
    const float* b2  = (const float*)d_in[8];

    const int N  = in_sizes[0] / 32;
    const int E  = in_sizes[1] / 2;
    const int NB = (N + TILE - 1) / TILE;     // 782 for N=50000
    float* out = (float*)d_out;

    const size_t rowB = (size_t)N * HID * sizeof(float);            // 12.8 MB
    const size_t vkB  = ((size_t)N * HID * 2 + 63) & ~(size_t)63;
    const size_t binB = ((size_t)E * sizeof(int) + 63) & ~(size_t)63;
    const size_t nbB  = ((size_t)(NB + 2) * sizeof(int) + 63) & ~(size_t)63;
    const size_t wc1B = ((size_t)32 * 128 * 2 + 63) & ~(size_t)63;
    const size_t wc2B = ((size_t)64 * 128 * 2 + 63) & ~(size_t)63;

    const int hBlk = 256;
    const int bBlk = (E + 256 * EPT - 1) / (256 * EPT);
    const int gBlk = 128;                     // mfma gemm: ~6 tiles/wave
    const int pBlk = (32 * 64 + 64 * 64 + 255) / 256;

    _Float16* wc1 = nullptr;
    _Float16* wc2 = nullptr;

    auto run = [&](G ga, G gb, int ny) {
        // bcnt arrays contiguous across graphs: one memset when ny==2
        hipMemsetAsync(ga.bcnt, 0, (size_t)ny * nbB, stream);
        hist_kernel<<<dim3(hBlk, ny), 256, 0, stream>>>(ga, gb, E, NB);
        scan_kernel<<<dim3(1, ny), 1024, 0, stream>>>(ga, gb, NB);
        bin_kernel <<<dim3(bBlk, ny), 256, 0, stream>>>(ga, gb, E, NB);
        gemm_mfma_kernel<32><<<dim3(gBlk, ny), 256, 0, stream>>>(ga, gb, wc1, b1, N);
        agg_kernel          <<<dim3(NB,   ny), 256, 0, stream>>>(ga, gb, N);
        gemm_mfma_kernel<64><<<dim3(gBlk, ny), 256, 0, stream>>>(ga, gb, wc2, b2, N);
        agg_kernel          <<<dim3(NB,   ny), 256, 0, stream>>>(ga, gb, N);
    };

    char* ws = (char*)d_ws;
    const size_t needBoth = 2 * rowB + 2 * vkB + 2 * binB + 6 * nbB + wc1B + wc2B;

    if (ws_size >= needBoth) {
        float* u0 = (float*)ws;                  ws += rowB;
        float* u1 = (float*)ws;                  ws += rowB;
        unsigned int* bin0 = (unsigned int*)ws;  ws += binB;
        unsigned int* bin1 = (unsigned int*)ws;  ws += binB;
        unsigned short* vk0 = (unsigned short*)ws;  ws += vkB;
        unsigned short* vk1 = (unsigned short*)ws;  ws += vkB;
        wc1 = (_Float16*)ws;                     ws += wc1B;
        wc2 = (_Float16*)ws;                     ws += wc2B;
        int* bcnt0 = (int*)ws;                   ws += nbB;
        int* bcnt1 = (int*)ws;                   ws += nbB;   // contiguous with bcnt0
        int* bptr0 = (int*)ws;                   ws += nbB;
        int* bptr1 = (int*)ws;                   ws += nbB;
        int* wp0   = (int*)ws;                   ws += nbB;
        int* wp1   = (int*)ws;

        G g0{x1, ei1, ei1 + E, bcnt0, bptr0, wp0, bin0, u0, vk0, out};
        G g1{x2, ei2, ei2 + E, bcnt1, bptr1, wp1, bin1, u1, vk1,
             out + (size_t)N * HID};
        prep_w_kernel<<<pBlk, 256, 0, stream>>>(W1, W2, wc1, wc2);
        run(g0, g1, 2);
    } else {
        // sequential fallback (~26 MB): one graph's buffers, reused
        float* u = (float*)ws;                   ws += rowB;
        unsigned int* bin = (unsigned int*)ws;   ws += binB;
        unsigned short* vk = (unsigned short*)ws;  ws += vkB;
        wc1 = (_Float16*)ws;                     ws += wc1B;
        wc2 = (_Float16*)ws;                     ws += wc2B;
        int* bcnt = (int*)ws;                    ws += nbB;
        int* bptr = (int*)ws;                    ws += nbB;
        int* wp   = (int*)ws;

        prep_w_kernel<<<pBlk, 256, 0, stream>>>(W1, W2, wc1, wc2);
        for (int g = 0; g < 2; ++g) {
            const int* ei = g ? ei2 : ei1;
            G gp{g ? x2 : x1, ei, ei + E, bcnt, bptr, wp, bin,
                 u, vk, out + (size_t)g * N * HID};
            run(gp, gp, 1);
        }
    }
}

// Round 10
// 285.390 us; speedup vs baseline: 1.5629x; 1.0054x over previous
//
#include <hip/hip_runtime.h>
#include <hip/hip_fp16.h>

// SiameseEdgeConvNet: 2-layer EdgeConv (max aggr) on two graphs, shared weights.
// N=50000, E=1.6e6, dims 32 -> 64 -> 64.
//
// Algebra: msg = relu([xi, xj-xi] @ W + b) = relu(xi@A + xj@B + b),
//   A=W_lo-W_hi, B=W_hi.  u = x@A + b, v = x@B per node; ReLU monotone =>
//   out[d] = relu(u[d] + max_{e: dst=d} v[src_e]);  empty segment -> 0
//   (matches jax isfinite->0 fixup).  PReLU input >= 0 -> identity -> skipped.
//
// R10: TILE 64->32 (dst>>5). R9's agg ran at Occupancy 53% with only 1564
//   blocks (~6/CU) — latency-bound, no pipe saturated. 3128 blocks (~12/CU,
//   8.3 KB LDS -> 8 blocks/CU cap = 100% wave occupancy) + smoother tail.
//   Everything else identical to R9 (MFMA gemm, pre-encoded fp16 sort keys,
//   channel-permuted vk, 16-bank-spread LDS atomicMax).

constexpr int HID   = 64;
constexpr int TILE  = 32;           // nodes per bucket (dst >> 5)
constexpr int TSH   = 5;            // log2(TILE)
constexpr int ASTR  = 65;           // LDS row stride (uints): base bank = r mod 32
constexpr int MAXNB = 2048;         // max buckets (N <= 65536)
constexpr int EPT   = 16;           // edges per thread in bin_kernel

typedef _Float16 half8 __attribute__((ext_vector_type(8)));
typedef float    f32x4 __attribute__((ext_vector_type(4)));

__device__ __forceinline__ unsigned short enc16(float f) {
    const __half h = __float2half_rn(f);
    const unsigned short b = *reinterpret_cast<const unsigned short*>(&h);
    return (b & 0x8000u) ? (unsigned short)~b : (unsigned short)(b | 0x8000u);
}
__device__ __forceinline__ float dec16(unsigned short k) {
    const unsigned short b =
        (k & 0x8000u) ? (unsigned short)(k ^ 0x8000u) : (unsigned short)~k;
    __half h;
    *reinterpret_cast<unsigned short*>(&h) = b;
    return __half2float(h);
}

struct G {                    // one graph's pointer set
    const float* x;           // [N,32] layer-1 input
    const int*   src;         // [E]
    const int*   dst;         // [E]
    int* bcnt;                // [NB]   bucket counts
    int* bptr;                // [NB+1] bucket offsets
    int* wp;                  // [NB]   bucket write pointers
    unsigned int* bin;        // [E]    packed records (src<<5 | dst&31)
    float*          u;        // [N,64] fp32
    unsigned short* vk;       // [N,64] fp16 sort keys, channel-permuted
    float*          out;      // [N,64] — h after layer 1, final after layer 2
};

// ---- weight prep: Wc[k][c] = (c<64 ? W_lo-W_hi : W_hi) in fp16, [K x 128] ----
__global__ __launch_bounds__(256) void prep_w_kernel(
    const float* __restrict__ W1, const float* __restrict__ W2,
    _Float16* __restrict__ Wc1, _Float16* __restrict__ Wc2)
{
    const int i = blockIdx.x * 256 + threadIdx.x;
    if (i < 32 * 64) {
        const int k = i >> 6, c = i & 63;
        const float lo = W1[k * 64 + c], hi = W1[(32 + k) * 64 + c];
        Wc1[k * 128 + c]      = (_Float16)(lo - hi);
        Wc1[k * 128 + 64 + c] = (_Float16)hi;
    }
    const int j = i - 32 * 64;
    if (j >= 0 && j < 64 * 64) {
        const int k = j >> 6, c = j & 63;
        const float lo = W2[k * 64 + c], hi = W2[(64 + k) * 64 + c];
        Wc2[k * 128 + c]      = (_Float16)(lo - hi);
        Wc2[k * 128 + 64 + c] = (_Float16)hi;
    }
}

// ---- bucket histogram (LDS-staged) ----
__global__ __launch_bounds__(256) void hist_kernel(G g0, G g1, int E, int NB) {
    const G g = blockIdx.y ? g1 : g0;
    __shared__ int h[MAXNB];
    for (int i = threadIdx.x; i < NB; i += 256) h[i] = 0;
    __syncthreads();
    int i = blockIdx.x * 256 + threadIdx.x;
    const int stride = gridDim.x * 256;
    for (; i < E; i += stride) atomicAdd(&h[g.dst[i] >> TSH], 1);
    __syncthreads();
    for (int t = threadIdx.x; t < NB; t += 256) {
        const int c = h[t];
        if (c) atomicAdd(&g.bcnt[t], c);
    }
}

// ---- exclusive scan over NB buckets -> bptr, wp (one block per graph) ----
__global__ __launch_bounds__(1024) void scan_kernel(G g0, G g1, int NB) {
    const G g = blockIdx.y ? g1 : g0;
    __shared__ int bufA[1024], bufB[1024];
    const int t = threadIdx.x;
    const int chunk = (NB + 1023) / 1024;
    const int beg = t * chunk, end = min(NB, beg + chunk);
    int s = 0;
    for (int i = beg; i < end; ++i) s += g.bcnt[i];
    bufA[t] = s;
    __syncthreads();
    int* in = bufA; int* out = bufB;
    for (int off = 1; off < 1024; off <<= 1) {
        out[t] = in[t] + (t >= off ? in[t - off] : 0);
        __syncthreads();
        int* tmp = in; in = out; out = tmp;
    }
    int run = (t == 0) ? 0 : in[t - 1];
    for (int i = beg; i < end; ++i) {
        g.bptr[i] = run;
        g.wp[i]   = run;
        run += g.bcnt[i];
    }
    if (t == 0) g.bptr[NB] = in[1023];
}

// ---- bin: block-reserved bucket scatter of packed records ----
__global__ __launch_bounds__(256) void bin_kernel(G g0, G g1, int E, int NB) {
    const G g = blockIdx.y ? g1 : g0;
    __shared__ int lh[MAXNB];   // local hist, then local write offset
    __shared__ int lb[MAXNB];   // reserved base per bucket
    for (int i = threadIdx.x; i < NB; i += 256) lh[i] = 0;
    __syncthreads();

    const int base = blockIdx.x * 256 * EPT;
    unsigned int rec[EPT];
    int bb[EPT];
    #pragma unroll
    for (int k = 0; k < EPT; ++k) {
        const int i = base + k * 256 + threadIdx.x;   // coalesced stream
        if (i < E) {
            const int d = g.dst[i];
            const int s = g.src[i];
            rec[k] = ((unsigned int)s << TSH) | (unsigned int)(d & (TILE - 1));
            bb[k]  = d >> TSH;
            atomicAdd(&lh[bb[k]], 1);
        } else bb[k] = -1;
    }
    __syncthreads();
    for (int t = threadIdx.x; t < NB; t += 256) {
        const int c = lh[t];
        lb[t] = c ? atomicAdd(&g.wp[t], c) : 0;
        lh[t] = 0;
    }
    __syncthreads();
    #pragma unroll
    for (int k = 0; k < EPT; ++k) {
        if (bb[k] >= 0) {
            const int off = atomicAdd(&lh[bb[k]], 1);
            g.bin[lb[bb[k]] + off] = rec[k];
        }
    }
}

// ---- MFMA node GEMM: [u|v](N x 128) = in(N x K) @ Wc(K x 128); u += bias ----
// v is emitted as fp16 sort keys in channel-permuted order:
//   uint2 slot m of a row = channels {m, m+16, m+32, m+48}.
template<int K>
__global__ __launch_bounds__(256) void gemm_mfma_kernel(
    G g0, G g1, const _Float16* __restrict__ Wc,
    const float* __restrict__ bias, int N)
{
    const G g = blockIdx.y ? g1 : g0;
    constexpr int KH = K / 32;                 // k-halves (1 or 2)
    const int lane = threadIdx.x & 63;
    const int m    = lane & 15;                // A row / D col-lane
    const int quad = lane >> 4;
    const int wid  = (blockIdx.x * 256 + threadIdx.x) >> 6;
    const int nW   = (gridDim.x * 256) >> 6;

    // B-frags: B[k=32h+quad*8+j][n=16t+m]
    half8 bf[8][KH];
    #pragma unroll
    for (int t = 0; t < 8; ++t)
        #pragma unroll
        for (int h = 0; h < KH; ++h)
            #pragma unroll
            for (int j = 0; j < 8; ++j)
                bf[t][h][j] = Wc[(h * 32 + quad * 8 + j) * 128 + t * 16 + m];

    float bv[4];
    #pragma unroll
    for (int t = 0; t < 4; ++t) bv[t] = bias[t * 16 + m];

    const float* __restrict__ inp = (K == 32) ? g.x : g.out;
    const int tiles = (N + 15) / 16;

    for (int tile = wid; tile < tiles; tile += nW) {
        const int nbase = tile * 16;
        const int nodeA = min(nbase + m, N - 1);
        const float4* rp = (const float4*)(inp + (size_t)nodeA * K);

        half8 a[KH];
        #pragma unroll
        for (int h = 0; h < KH; ++h) {
            const float4 f0 = rp[h * 8 + quad * 2];
            const float4 f1 = rp[h * 8 + quad * 2 + 1];
            a[h][0] = (_Float16)f0.x; a[h][1] = (_Float16)f0.y;
            a[h][2] = (_Float16)f0.z; a[h][3] = (_Float16)f0.w;
            a[h][4] = (_Float16)f1.x; a[h][5] = (_Float16)f1.y;
            a[h][6] = (_Float16)f1.z; a[h][7] = (_Float16)f1.w;
        }

        f32x4 acc[8];
        #pragma unroll
        for (int t = 0; t < 8; ++t) {
            acc[t] = (f32x4){0.f, 0.f, 0.f, 0.f};
            #pragma unroll
            for (int h = 0; h < KH; ++h)
                acc[t] = __builtin_amdgcn_mfma_f32_16x16x32_f16(
                    a[h], bf[t][h], acc[t], 0, 0, 0);
        }

        // D[m=quad*4+r][n=lane&15]
        #pragma unroll
        for (int r = 0; r < 4; ++r) {
            const int node = nbase + quad * 4 + r;
            if (node < N) {
                float* urow = g.u + (size_t)node * HID;
                #pragma unroll
                for (int t = 0; t < 4; ++t)
                    urow[t * 16 + m] = acc[t][r] + bv[t];
                // v: keys for channels {m, m+16, m+32, m+48} -> uint2 slot m
                const unsigned int e0 = enc16(acc[4][r]);
                const unsigned int e1 = enc16(acc[5][r]);
                const unsigned int e2 = enc16(acc[6][r]);
                const unsigned int e3 = enc16(acc[7][r]);
                uint2 pack;
                pack.x = (e1 << 16) | e0;
                pack.y = (e3 << 16) | e2;
                ((uint2*)(g.vk + (size_t)node * HID))[m] = pack;
            }
        }
    }
}

// ---- aggregate: one block per 32-node tile, LDS atomicMax on 32-bit keys ----
__global__ __launch_bounds__(256) void agg_kernel(G g0, G g1, int N) {
    const G g = blockIdx.y ? g1 : g0;
    __shared__ unsigned int agg[TILE * ASTR];   // 32*65*4 = 8320 B
    for (int i = threadIdx.x; i < TILE * ASTR; i += 256) agg[i] = 0u;
    __syncthreads();

    const int b   = blockIdx.x;
    const int beg = g.bptr[b], end = g.bptr[b + 1];
    const int grp = threadIdx.x >> 4;           // 16 groups of 16 lanes
    const int sub = threadIdx.x & 15;
    const uint2* __restrict__ vk2 = (const uint2*)g.vk;  // 8 B = 4 keys/lane

    // channels {sub, sub+16, sub+32, sub+48}: atomics at row + sub + 16i
    // -> 16 consecutive banks per group
    #define PUSH(RAW, REC)                                                   \
    {                                                                        \
        unsigned int* row = &agg[((REC) & (TILE - 1u)) * ASTR + sub];        \
        atomicMax(row,      (RAW).x << 16);                                  \
        atomicMax(row + 16, (RAW).x & 0xFFFF0000u);                          \
        atomicMax(row + 32, (RAW).y << 16);                                  \
        atomicMax(row + 48, (RAW).y & 0xFFFF0000u);                          \
    }

    int r = beg + grp;
    for (; r + 48 < end; r += 64) {             // 4 gather chains in flight
        const unsigned int q0 = g.bin[r],      q1 = g.bin[r + 16];
        const unsigned int q2 = g.bin[r + 32], q3 = g.bin[r + 48];
        const uint2 a0 = vk2[(size_t)(q0 >> TSH) * 16 + sub];
        const uint2 a1 = vk2[(size_t)(q1 >> TSH) * 16 + sub];
        const uint2 a2 = vk2[(size_t)(q2 >> TSH) * 16 + sub];
        const uint2 a3 = vk2[(size_t)(q3 >> TSH) * 16 + sub];
        PUSH(a0, q0) PUSH(a1, q1) PUSH(a2, q2) PUSH(a3, q3)
    }
    for (; r < end; r += 16) {
        const unsigned int q0 = g.bin[r];
        const uint2 a0 = vk2[(size_t)(q0 >> TSH) * 16 + sub];
        PUSH(a0, q0)
    }
    #undef PUSH
    __syncthreads();

    const int nodeBase = b * TILE;
    for (int i = threadIdx.x; i < TILE * HID; i += 256) {   // 8 iters, coalesced
        const int nl = i >> 6, ch = i & 63;
        const int node = nodeBase + nl;
        if (node < N) {
            const unsigned int k = agg[nl * ASTR + ch];
            float rlt = 0.f;                                  // empty -> 0
            if (k) rlt = fmaxf(g.u[(size_t)node * HID + ch] +
                               dec16((unsigned short)(k >> 16)), 0.f);
            g.out[(size_t)node * HID + ch] = rlt;
        }
    }
}

// ---------------- orchestration ----------------

extern "C" void kernel_launch(void* const* d_in, const int* in_sizes, int n_in,
                              void* d_out, int out_size, void* d_ws, size_t ws_size,
                              hipStream_t stream) {
    const float* x1  = (const float*)d_in[0];
    const int*   ei1 = (const int*)d_in[1];   // [2,E]: src row then dst row
    const float* x2  = (const float*)d_in[2];
    const int*   ei2 = (const int*)d_in[3];
    const float* W1  = (const float*)d_in[4];
    const float* b1  = (const float*)d_in[5];
    // d_in[6] = prelu_a: unused (identity on >=0)
    const float* W2  = (const float*)d_in[7];
    const float* b2  = (const float*)d_in[8];

    const int N  = in_sizes[0] / 32;
    const int E  = in_sizes[1] / 2;
    const int NB = (N + TILE - 1) / TILE;     // 1563 for N=50000
    float* out = (float*)d_out;

    const size_t rowB = (size_t)N * HID * sizeof(float);            // 12.8 MB
    const size_t vkB  = ((size_t)N * HID * 2 + 63) & ~(size_t)63;
    const size_t binB = ((size_t)E * sizeof(int) + 63) & ~(size_t)63;
    const size_t nbB  = ((size_t)(NB + 2) * sizeof(int) + 63) & ~(size_t)63;
    const size_t wc1B = ((size_t)32 * 128 * 2 + 63) & ~(size_t)63;
    const size_t wc2B = ((size_t)64 * 128 * 2 + 63) & ~(size_t)63;

    const int hBlk = 256;
    const int bBlk = (E + 256 * EPT - 1) / (256 * EPT);
    const int gBlk = 128;                     // mfma gemm: ~6 tiles/wave
    const int pBlk = (32 * 64 + 64 * 64 + 255) / 256;

    _Float16* wc1 = nullptr;
    _Float16* wc2 = nullptr;

    auto run = [&](G ga, G gb, int ny) {
        // bcnt arrays contiguous across graphs: one memset when ny==2
        hipMemsetAsync(ga.bcnt, 0, (size_t)ny * nbB, stream);
        hist_kernel<<<dim3(hBlk, ny), 256, 0, stream>>>(ga, gb, E, NB);
        scan_kernel<<<dim3(1, ny), 1024, 0, stream>>>(ga, gb, NB);
        bin_kernel <<<dim3(bBlk, ny), 256, 0, stream>>>(ga, gb, E, NB);
        gemm_mfma_kernel<32><<<dim3(gBlk, ny), 256, 0, stream>>>(ga, gb, wc1, b1, N);
        agg_kernel          <<<dim3(NB,   ny), 256, 0, stream>>>(ga, gb, N);
        gemm_mfma_kernel<64><<<dim3(gBlk, ny), 256, 0, stream>>>(ga, gb, wc2, b2, N);
        agg_kernel          <<<dim3(NB,   ny), 256, 0, stream>>>(ga, gb, N);
    };

    char* ws = (char*)d_ws;
    const size_t needBoth = 2 * rowB + 2 * vkB + 2 * binB + 6 * nbB + wc1B + wc2B;

    if (ws_size >= needBoth) {
        float* u0 = (float*)ws;                  ws += rowB;
        float* u1 = (float*)ws;                  ws += rowB;
        unsigned int* bin0 = (unsigned int*)ws;  ws += binB;
        unsigned int* bin1 = (unsigned int*)ws;  ws += binB;
        unsigned short* vk0 = (unsigned short*)ws;  ws += vkB;
        unsigned short* vk1 = (unsigned short*)ws;  ws += vkB;
        wc1 = (_Float16*)ws;                     ws += wc1B;
        wc2 = (_Float16*)ws;                     ws += wc2B;
        int* bcnt0 = (int*)ws;                   ws += nbB;
        int* bcnt1 = (int*)ws;                   ws += nbB;   // contiguous with bcnt0
        int* bptr0 = (int*)ws;                   ws += nbB;
        int* bptr1 = (int*)ws;                   ws += nbB;
        int* wp0   = (int*)ws;                   ws += nbB;
        int* wp1   = (int*)ws;

        G g0{x1, ei1, ei1 + E, bcnt0, bptr0, wp0, bin0, u0, vk0, out};
        G g1{x2, ei2, ei2 + E, bcnt1, bptr1, wp1, bin1, u1, vk1,
             out + (size_t)N * HID};
        prep_w_kernel<<<pBlk, 256, 0, stream>>>(W1, W2, wc1, wc2);
        run(g0, g1, 2);
    } else {
        // sequential fallback (~26 MB): one graph's buffers, reused
        float* u = (float*)ws;                   ws += rowB;
        unsigned int* bin = (unsigned int*)ws;   ws += binB;
        unsigned short* vk = (unsigned short*)ws;  ws += vkB;
        wc1 = (_Float16*)ws;                     ws += wc1B;
        wc2 = (_Float16*)ws;                     ws += wc2B;
        int* bcnt = (int*)ws;                    ws += nbB;
        int* bptr = (int*)ws;                    ws += nbB;
        int* wp   = (int*)ws;

        prep_w_kernel<<<pBlk, 256, 0, stream>>>(W1, W2, wc1, wc2);
        for (int g = 0; g < 2; ++g) {
            const int* ei = g ? ei2 : ei1;
            G gp{g ? x2 : x1, ei, ei + E, bcnt, bptr, wp, bin,
                 u, vk, out + (size_t)g * N * HID};
            run(gp, gp, 1);
        }
    }
}